// Round 3
// baseline (88669.824 us; speedup 1.0000x reference)
//
#include <hip/hip_runtime.h>
#include <math.h>

// Problem constants (reference: B,T,D,H = 32,512,512,1024)
#define B_  32
#define T_  512
#define D_  512
#define H_  1024
#define FH  4096   // 4*H

// ---------------------------------------------------------------------------
// Workspace layout (bytes):
//   wht  : [4096][1024] fp32 (transposed Wh)   = 16,777,216  @ 0
//   hbuf : [2][32][1024] fp32                  =    262,144  @ 16,777,216
//   cbuf : [32][1024] fp32                     =    131,072  @ 17,039,360
//   flags: 256 x u32 (+pad)                    =      4,096  @ 17,170,432
//   xgc  : [Tc][32][4096] fp32                 = Tc*524,288  @ 17,174,528
// Tc in {512, 64, 16, 4} -> totals {285.6, 50.7, 25.6, 19.3} MB
// ---------------------------------------------------------------------------

// ---- transpose Wh[1024][4096] -> WhT[4096][1024] --------------------------
__global__ void transpose_wh(const float* __restrict__ wh, float* __restrict__ wht) {
    __shared__ float tl[32][33];
    const int n0 = blockIdx.x * 32;   // gridDim.x = 128
    const int k0 = blockIdx.y * 32;   // gridDim.y = 32
    const int tx = threadIdx.x, ty = threadIdx.y;   // block (32,8)
#pragma unroll
    for (int j = 0; j < 4; ++j) {
        int r = ty + j * 8;
        tl[r][tx] = wh[(size_t)(k0 + r) * FH + n0 + tx];
    }
    __syncthreads();
#pragma unroll
    for (int j = 0; j < 4; ++j) {
        int r = ty + j * 8;
        wht[(size_t)(n0 + r) * H_ + k0 + tx] = tl[tx][r];
    }
}

// ---- fp32 GEMM + bias for a chunk of timesteps ----------------------------
// xgc[r][n] = sum_k A[arow(r)][k]*W[k][n] + bias[n],  r in [0,Tc*32)
// arow(r) = (r&31)*512 + t0 + (r>>5)  (input row b*T+t); xgc slab = [t-t0][b].
__global__ __launch_bounds__(256) void gemm_bias_chunk(
    const float* __restrict__ A, const float* __restrict__ W,
    const float* __restrict__ bias, float* __restrict__ out, int K, int t0) {
    __shared__ float As[16 * 132];
    __shared__ float Bs[16 * 132];
    const int t  = threadIdx.x;
    const int tn = t & 15, tm = t >> 4;
    const int n0 = blockIdx.x * 128;
    const int m0 = blockIdx.y * 128;

    float acc[8][8];
#pragma unroll
    for (int i = 0; i < 8; ++i)
#pragma unroll
        for (int j = 0; j < 8; ++j) acc[i][j] = 0.f;

    for (int k0 = 0; k0 < K; k0 += 16) {
#pragma unroll
        for (int i = 0; i < 2; ++i) {   // A tile 128x16 -> As[k][m]
            int fid = t + i * 256;
            int m = fid >> 2, cc = fid & 3;
            int r = m0 + m;
            int arow = (r & 31) * 512 + t0 + (r >> 5);
            float4 av = *(const float4*)(A + (size_t)arow * K + k0 + cc * 4);
            As[(cc * 4 + 0) * 132 + m] = av.x;
            As[(cc * 4 + 1) * 132 + m] = av.y;
            As[(cc * 4 + 2) * 132 + m] = av.z;
            As[(cc * 4 + 3) * 132 + m] = av.w;
        }
#pragma unroll
        for (int i = 0; i < 2; ++i) {   // B tile 16x128 -> Bs[k][n]
            int fid = t + i * 256;
            int kk = fid >> 5, c = fid & 31;
            *(float4*)(Bs + kk * 132 + c * 4) =
                *(const float4*)(W + (size_t)(k0 + kk) * FH + n0 + c * 4);
        }
        __syncthreads();
#pragma unroll
        for (int kk = 0; kk < 16; ++kk) {
            float4 a0 = *(const float4*)(As + kk * 132 + tm * 8);
            float4 a1 = *(const float4*)(As + kk * 132 + tm * 8 + 4);
            float4 b0 = *(const float4*)(Bs + kk * 132 + tn * 4);
            float4 b1 = *(const float4*)(Bs + kk * 132 + 64 + tn * 4);
            float am[8] = {a0.x, a0.y, a0.z, a0.w, a1.x, a1.y, a1.z, a1.w};
            float bn[8] = {b0.x, b0.y, b0.z, b0.w, b1.x, b1.y, b1.z, b1.w};
#pragma unroll
            for (int mm = 0; mm < 8; ++mm)
#pragma unroll
                for (int nn = 0; nn < 8; ++nn) acc[mm][nn] += am[mm] * bn[nn];
        }
        __syncthreads();
    }

    float4 bb0 = *(const float4*)(bias + n0 + tn * 4);
    float4 bb1 = *(const float4*)(bias + n0 + 64 + tn * 4);
#pragma unroll
    for (int mm = 0; mm < 8; ++mm) {
        size_t orow = (size_t)(m0 + tm * 8 + mm);
        float4 v0, v1;
        v0.x = acc[mm][0] + bb0.x; v0.y = acc[mm][1] + bb0.y;
        v0.z = acc[mm][2] + bb0.z; v0.w = acc[mm][3] + bb0.w;
        v1.x = acc[mm][4] + bb1.x; v1.y = acc[mm][5] + bb1.y;
        v1.z = acc[mm][6] + bb1.z; v1.w = acc[mm][7] + bb1.w;
        *(float4*)(out + orow * FH + n0 + tn * 4)      = v0;
        *(float4*)(out + orow * FH + n0 + 64 + tn * 4) = v1;
    }
}

// ---- persistent LSTM scan over a segment of Tc timesteps ------------------
// 256 blocks x 512 threads; block owns 4 h-cols (hc0..hc0+3) = 16 gate rows
// (rr = gt*4 + col).  Thread: rg=t&3 (its GATE, all 4 cols), sl=(t>>2)&31
// (K-slice: k = ch*128 + sl*4), bg=t>>7 (8 batches). Wh slice lives in 128
// VGPRs per thread for the whole segment. Cross-block step sync: monotonic
// per-block flags (agent-scope acquire/release), h double-buffered in global.
__global__ __launch_bounds__(512, 2) void lstm_scan(
    const float* __restrict__ wht,    // [4096][1024]
    const float* __restrict__ xgc,    // [Tc][32][4096]
    float* __restrict__ hbuf,         // [2][32][1024]
    float* __restrict__ cbuf,         // [32][1024]
    unsigned* __restrict__ flags,     // [256]
    float* __restrict__ y,            // out base: [B][T][H]
    int t0, int Tc)
{
    __shared__ float4 hs4[2][32 * 33];   // 33,792 B : h-chunk double buffer
    __shared__ float  sc[32 * 32 * 24];  // 98,304 B : partials [(b,sl)][rr pad24]
    __shared__ float  g[16 * 32];        //  2,048 B : gates [rr][b]

    const int tau = threadIdx.x;
    const int blk = blockIdx.x;
    const int hc0 = blk * 4;
    const int rg  = tau & 3;
    const int sl  = (tau >> 2) & 31;
    const int bg  = tau >> 7;

    // ---- Wh slice -> registers (once per segment) ----
    const float4* wht4 = (const float4*)wht;
    float4 w4[4][8];
#pragma unroll
    for (int gi = 0; gi < 4; ++gi) {
        int grow = rg * H_ + hc0 + gi;
#pragma unroll
        for (int ch = 0; ch < 8; ++ch)
            w4[gi][ch] = wht4[(size_t)grow * 256 + ch * 32 + sl];
    }

    // ---- c state -> registers of activation threads ----
    float4 creg = make_float4(0.f, 0.f, 0.f, 0.f);
    if (tau < 32) creg = ((const float4*)cbuf)[tau * 256 + blk];

    const int fid0 = tau, fid1 = tau + 512;
    const int b0s = fid0 >> 5, c0s = fid0 & 31;
    const int b1s = fid1 >> 5, c1s = fid1 & 31;

    for (int i = 0; i < Tc; ++i) {
        const int t = t0 + i;
        const float4* hp4 = (const float4*)(hbuf + (size_t)(t & 1) * (32 * 1024));
        float*        hn  = hbuf + (size_t)((t + 1) & 1) * (32 * 1024);
        const float*  xg_t = xgc + (size_t)i * (32 * 4096);

        // wait until every block finished step t-1 (h_t fully written)
        if (t > 0 && tau < 256) {
            while (__hip_atomic_load(flags + tau, __ATOMIC_ACQUIRE,
                                     __HIP_MEMORY_SCOPE_AGENT) < (unsigned)t)
                __builtin_amdgcn_s_sleep(1);
        }
        __syncthreads();

        float acc[4][8];
#pragma unroll
        for (int gi = 0; gi < 4; ++gi)
#pragma unroll
            for (int bi = 0; bi < 8; ++bi) acc[gi][bi] = 0.f;

        // stage chunk 0
        float4 p0 = hp4[b0s * 256 + c0s];
        float4 p1 = hp4[b1s * 256 + c1s];
        hs4[0][b0s * 33 + c0s] = p0;
        hs4[0][b1s * 33 + c1s] = p1;
        __syncthreads();

#pragma unroll
        for (int ch = 0; ch < 8; ++ch) {
            if (ch < 7) {   // prefetch next chunk from global (hidden by FMAs)
                p0 = hp4[b0s * 256 + (ch + 1) * 32 + c0s];
                p1 = hp4[b1s * 256 + (ch + 1) * 32 + c1s];
            }
            const float4* hb = &hs4[ch & 1][0];
#pragma unroll
            for (int bi = 0; bi < 8; ++bi) {
                float4 hv = hb[(bg * 8 + bi) * 33 + sl];
#pragma unroll
                for (int gi = 0; gi < 4; ++gi) {
                    float4 w = w4[gi][ch];
                    acc[gi][bi] += w.x * hv.x + w.y * hv.y + w.z * hv.z + w.w * hv.w;
                }
            }
            if (ch < 7) {
                hs4[(ch + 1) & 1][b0s * 33 + c0s] = p0;
                hs4[(ch + 1) & 1][b1s * 33 + c1s] = p1;
            }
            __syncthreads();
        }

        // partials -> LDS  (rr = rg*4 + gi packed as f4)
#pragma unroll
        for (int bi = 0; bi < 8; ++bi) {
            int b = bg * 8 + bi;
            *(float4*)&sc[(b * 32 + sl) * 24 + rg * 4] =
                make_float4(acc[0][bi], acc[1][bi], acc[2][bi], acc[3][bi]);
        }
        __syncthreads();

        // reduce over 32 slices, add xg
        {
            int rr = tau & 15, b = tau >> 4;
            float s = 0.f;
#pragma unroll
            for (int j = 0; j < 32; ++j) s += sc[(b * 32 + j) * 24 + rr];
            int gt = rr >> 2, col = rr & 3;
            s += xg_t[b * FH + gt * H_ + hc0 + col];
            g[rr * 32 + b] = s;
        }
        __syncthreads();

        // activation: thread b handles its 4 cols; c kept in registers
        if (tau < 32) {
            int b = tau;
            float4 hv4;
            float* cc = (float*)&creg;
            float* hh = (float*)&hv4;
#pragma unroll
            for (int col = 0; col < 4; ++col) {
                float vi = g[(0 * 4 + col) * 32 + b];
                float vf = g[(1 * 4 + col) * 32 + b];
                float vg = g[(2 * 4 + col) * 32 + b];
                float vo = g[(3 * 4 + col) * 32 + b];
                float si = 1.f / (1.f + __expf(-vi));
                float sf = 1.f / (1.f + __expf(-vf));
                float so = 1.f / (1.f + __expf(-vo));
                float ag = fabsf(vg), eg = __expf(-2.f * ag);
                float tg = (1.f - eg) / (1.f + eg); tg = vg < 0.f ? -tg : tg;
                float cn = sf * cc[col] + si * tg;
                cc[col] = cn;
                float ac = fabsf(cn), ec = __expf(-2.f * ac);
                float th = (1.f - ec) / (1.f + ec); th = cn < 0.f ? -th : th;
                hh[col] = so * th;
            }
            ((float4*)hn)[b * 256 + blk] = hv4;
            ((float4*)y)[(size_t)b * (T_ * H_ / 4) + t * (H_ / 4) + blk] = hv4;
        }
        __syncthreads();   // drains h stores (vmcnt) block-wide
        if (tau == 0)
            __hip_atomic_store(flags + blk, (unsigned)(t + 1), __ATOMIC_RELEASE,
                               __HIP_MEMORY_SCOPE_AGENT);
    }

    if (tau < 32) ((float4*)cbuf)[tau * 256 + blk] = creg;
}

// ---------------------------------------------------------------------------
extern "C" void kernel_launch(void* const* d_in, const int* in_sizes, int n_in,
                              void* d_out, int out_size, void* d_ws, size_t ws_size,
                              hipStream_t stream) {
    (void)in_sizes; (void)n_in; (void)out_size;
    const float* x   = (const float*)d_in[0];
    const float* Wx0 = (const float*)d_in[1];
    const float* Wh0 = (const float*)d_in[2];
    const float* b0  = (const float*)d_in[3];
    const float* Wx1 = (const float*)d_in[4];
    const float* Wh1 = (const float*)d_in[5];
    const float* b1  = (const float*)d_in[6];
    float* out = (float*)d_out;

    char* ws = (char*)d_ws;
    float*    wht   = (float*)(ws);
    float*    hbuf  = (float*)(ws + 16777216ull);
    float*    cbuf  = (float*)(ws + 17039360ull);
    unsigned* flags = (unsigned*)(ws + 17170432ull);
    float*    xgc   = (float*)(ws + 17174528ull);

    const size_t base = 17174528ull;
    int Tc;
    if      (ws_size >= base + 512ull * 524288ull) Tc = 512;
    else if (ws_size >= base +  64ull * 524288ull) Tc = 64;
    else if (ws_size >= base +  16ull * 524288ull) Tc = 16;
    else                                           Tc = 4;

    for (int layer = 0; layer < 2; ++layer) {
        const float* Aptr = layer ? out : x;
        const float* Wxp  = layer ? Wx1 : Wx0;
        const float* Whp  = layer ? Wh1 : Wh0;
        const float* bp   = layer ? b1  : b0;
        const int    K    = layer ? H_  : D_;

        transpose_wh<<<dim3(128, 32), dim3(32, 8), 0, stream>>>(Whp, wht);
        hipMemsetAsync(hbuf, 0, 262144, stream);
        hipMemsetAsync(cbuf, 0, 131072, stream);
        hipMemsetAsync(flags, 0, 4096, stream);

        for (int t0 = 0; t0 < T_; t0 += Tc) {
            // Layer 1 reads out[] rows t in [t0,t0+Tc) only — rows its own
            // scan hasn't overwritten yet -> stream-order safe.
            gemm_bias_chunk<<<dim3(32, Tc / 4), 256, 0, stream>>>(
                Aptr, Wxp, bp, xgc, K, t0);
            lstm_scan<<<256, 512, 0, stream>>>(
                wht, xgc, hbuf, cbuf, flags, out, t0, Tc);
        }
    }
}

// Round 5
// 36196.729 us; speedup vs baseline: 2.4497x; 2.4497x over previous
//
#include <hip/hip_runtime.h>
#include <math.h>

// Problem constants (reference: B,T,D,H = 32,512,512,1024)
#define B_  32
#define T_  512
#define D_  512
#define H_  1024
#define FH  4096   // 4*H

// ---------------------------------------------------------------------------
// Workspace layout (bytes):
//   wht  : [4096][1024] fp32 (transposed Wh)   = 16,777,216  @ 0
//   hbuf : [2][32][1024] fp32                  =    262,144  @ 16,777,216
//   cbuf : [32][1024] fp32                     =    131,072  @ 17,039,360
//   flags: 256 x u32 (+pad)                    =      4,096  @ 17,170,432
//   xgc  : [Tc][32][4096] fp32                 = Tc*524,288  @ 17,174,528
// Tc in {512,128,64,16,4} -> {285.6, 84.3, 50.7, 25.6, 19.3} MB
// R2 evidence: Tc=64 tier ran -> ws_size >= 50.7 MB.
// ---------------------------------------------------------------------------

// ---- transpose Wh[1024][4096] -> WhT[4096][1024] --------------------------
__global__ void transpose_wh(const float* __restrict__ wh, float* __restrict__ wht) {
    __shared__ float tl[32][33];
    const int n0 = blockIdx.x * 32;   // gridDim.x = 128
    const int k0 = blockIdx.y * 32;   // gridDim.y = 32
    const int tx = threadIdx.x, ty = threadIdx.y;   // block (32,8)
#pragma unroll
    for (int j = 0; j < 4; ++j) {
        int r = ty + j * 8;
        tl[r][tx] = wh[(size_t)(k0 + r) * FH + n0 + tx];
    }
    __syncthreads();
#pragma unroll
    for (int j = 0; j < 4; ++j) {
        int r = ty + j * 8;
        wht[(size_t)(n0 + r) * H_ + k0 + tx] = tl[tx][r];
    }
}

// ---- fp32 GEMM + bias for a chunk of timesteps (64x128 tiles) -------------
// xgc[r][n] = sum_k A[arow(r)][k]*W[k][n] + bias[n],  r in [0,Tc*32)
// arow(r) = (r&31)*512 + t0 + (r>>5).  Grid: dim3(32, Tc/2) -> full device.
__global__ __launch_bounds__(256) void gemm_bias_chunk(
    const float* __restrict__ A, const float* __restrict__ W,
    const float* __restrict__ bias, float* __restrict__ out, int K, int t0) {
    __shared__ float As[16 * 68];    // As[k][m], m-tile 64, pad 68
    __shared__ float Bs[16 * 132];   // Bs[k][n], n-tile 128
    const int t  = threadIdx.x;
    const int tn = t & 15, tm = t >> 4;
    const int n0 = blockIdx.x * 128;
    const int m0 = blockIdx.y * 64;

    float acc[4][8];
#pragma unroll
    for (int i = 0; i < 4; ++i)
#pragma unroll
        for (int j = 0; j < 8; ++j) acc[i][j] = 0.f;

    for (int k0 = 0; k0 < K; k0 += 16) {
        {   // A tile 64x16 -> As[k][m]; one float4 per thread
            int m = t >> 2, cc = t & 3;
            int r = m0 + m;
            int arow = (r & 31) * 512 + t0 + (r >> 5);
            float4 av = *(const float4*)(A + (size_t)arow * K + k0 + cc * 4);
            As[(cc * 4 + 0) * 68 + m] = av.x;
            As[(cc * 4 + 1) * 68 + m] = av.y;
            As[(cc * 4 + 2) * 68 + m] = av.z;
            As[(cc * 4 + 3) * 68 + m] = av.w;
        }
#pragma unroll
        for (int i = 0; i < 2; ++i) {   // B tile 16x128 -> Bs[k][n]
            int fid = t + i * 256;
            int kk = fid >> 5, c = fid & 31;
            *(float4*)(Bs + kk * 132 + c * 4) =
                *(const float4*)(W + (size_t)(k0 + kk) * FH + n0 + c * 4);
        }
        __syncthreads();
#pragma unroll
        for (int kk = 0; kk < 16; ++kk) {
            float4 a  = *(const float4*)(As + kk * 68 + tm * 4);
            float4 b0 = *(const float4*)(Bs + kk * 132 + tn * 4);
            float4 b1 = *(const float4*)(Bs + kk * 132 + 64 + tn * 4);
            float am[4] = {a.x, a.y, a.z, a.w};
            float bn[8] = {b0.x, b0.y, b0.z, b0.w, b1.x, b1.y, b1.z, b1.w};
#pragma unroll
            for (int mm = 0; mm < 4; ++mm)
#pragma unroll
                for (int nn = 0; nn < 8; ++nn) acc[mm][nn] += am[mm] * bn[nn];
        }
        __syncthreads();
    }

    float4 bb0 = *(const float4*)(bias + n0 + tn * 4);
    float4 bb1 = *(const float4*)(bias + n0 + 64 + tn * 4);
#pragma unroll
    for (int mm = 0; mm < 4; ++mm) {
        size_t orow = (size_t)(m0 + tm * 4 + mm);
        float4 v0, v1;
        v0.x = acc[mm][0] + bb0.x; v0.y = acc[mm][1] + bb0.y;
        v0.z = acc[mm][2] + bb0.z; v0.w = acc[mm][3] + bb0.w;
        v1.x = acc[mm][4] + bb1.x; v1.y = acc[mm][5] + bb1.y;
        v1.z = acc[mm][6] + bb1.z; v1.w = acc[mm][7] + bb1.w;
        *(float4*)(out + orow * FH + n0 + tn * 4)      = v0;
        *(float4*)(out + orow * FH + n0 + 64 + tn * 4) = v1;
    }
}

// ---- persistent LSTM scan over a segment of Tc timesteps ------------------
// 256 blocks x 512 threads; block owns 4 h-cols -> 16 gate rows rr=gate*4+col.
// Thread map: rrg=tau&7 (rr pair 2rrg,2rrg+1), slq=(tau>>3)&7, wave=tau>>6,
// slh=wave&3, bg=wave>>2; sl=slh*8+slq (k = ch*128 + sl*4); 16 batches/thread.
// Wh slice = w4[2][8] = 64 VGPRs, loaded once per launch (registers!).
// Sync: RELAXED flag polls (no per-poll L2 inv) + one acq/rel fence per step.
__global__ __launch_bounds__(512, 2) __attribute__((amdgpu_waves_per_eu(2, 2)))
void lstm_scan(
    const float* __restrict__ wht,    // [4096][1024]
    const float* __restrict__ xgc,    // [Tc][32][4096]
    float* __restrict__ hbuf,         // [2][32][1024]
    float* __restrict__ cbuf,         // [32][1024]
    unsigned* __restrict__ flags,     // [256], monotonic step counters
    float* __restrict__ y,            // out base: [B][T][H]
    int t0, int Tc)
{
    __shared__ float4 hs4[2][32 * 33];      // 33,792 B : h-chunk double buffer
    __shared__ float  sc[32 * 32 * 18];     // 73,728 B : partials [(b,sl)][rr]
    __shared__ float  g[16 * 32];           //  2,048 B : gates [rr][b]

    const int tau = threadIdx.x;
    const int blk = blockIdx.x;
    const int hc0 = blk * 4;
    const int rrg = tau & 7;
    const int slq = (tau >> 3) & 7;
    const int wv  = tau >> 6;
    const int sl  = (wv & 3) * 8 + slq;
    const int bg  = wv >> 2;

    // ---- Wh slice -> 64 VGPRs (once per launch) ----
    const float4* wht4 = (const float4*)wht;
    float4 w4[2][8];
#pragma unroll
    for (int p = 0; p < 2; ++p) {
        int rr = rrg * 2 + p;
        int grow = (rr >> 2) * H_ + hc0 + (rr & 3);
#pragma unroll
        for (int ch = 0; ch < 8; ++ch)
            w4[p][ch] = wht4[(size_t)grow * 256 + ch * 32 + sl];
    }

    // ---- c state in activation-thread registers ----
    float4 creg = make_float4(0.f, 0.f, 0.f, 0.f);
    if (tau < 32) creg = ((const float4*)cbuf)[tau * 256 + blk];

    const int b0s = tau >> 5,        c0s = tau & 31;
    const int b1s = (tau + 512) >> 5, c1s = tau & 31;

    for (int i = 0; i < Tc; ++i) {
        const int t = t0 + i;
        const float4* hp4 = (const float4*)(hbuf + (size_t)(t & 1) * (32 * 1024));
        float*        hn  = hbuf + (size_t)((t + 1) & 1) * (32 * 1024);
        const float*  xg_t = xgc + (size_t)i * (32 * 4096);

        // ---- device barrier for step t (h_t fully published) ----
        if (t > 0) {
            if (tau < 256) {
                while (__hip_atomic_load(flags + tau, __ATOMIC_RELAXED,
                                         __HIP_MEMORY_SCOPE_AGENT) < (unsigned)t)
                    __builtin_amdgcn_s_sleep(8);
            }
            __syncthreads();
            // one inv per step (NOT per poll) -> L2 stays warm otherwise
            __builtin_amdgcn_fence(__ATOMIC_ACQUIRE, "agent");
        }

        float acc[2][16];
#pragma unroll
        for (int p = 0; p < 2; ++p)
#pragma unroll
            for (int bi = 0; bi < 16; ++bi) acc[p][bi] = 0.f;

        // stage chunk 0 (32 batches x 128 floats)
        float4 p0 = hp4[b0s * 256 + c0s];
        float4 p1 = hp4[b1s * 256 + c1s];
        hs4[0][b0s * 33 + c0s] = p0;
        hs4[0][b1s * 33 + c1s] = p1;
        __syncthreads();

#pragma unroll
        for (int ch = 0; ch < 8; ++ch) {
            if (ch < 7) {   // prefetch next chunk (hidden under FMAs)
                p0 = hp4[b0s * 256 + (ch + 1) * 32 + c0s];
                p1 = hp4[b1s * 256 + (ch + 1) * 32 + c1s];
            }
            const float4* hb = &hs4[ch & 1][0];
#pragma unroll
            for (int bi = 0; bi < 16; ++bi) {
                float4 hv = hb[(bg * 16 + bi) * 33 + sl];
                float4 wa = w4[0][ch], wb = w4[1][ch];
                acc[0][bi] += wa.x * hv.x + wa.y * hv.y + wa.z * hv.z + wa.w * hv.w;
                acc[1][bi] += wb.x * hv.x + wb.y * hv.y + wb.z * hv.z + wb.w * hv.w;
            }
            if (ch < 7) {
                hs4[(ch + 1) & 1][b0s * 33 + c0s] = p0;
                hs4[(ch + 1) & 1][b1s * 33 + c1s] = p1;
            }
            __syncthreads();
        }

        // partials -> sc[(b*32+sl)*18 + rr] (float2 per thread per batch)
#pragma unroll
        for (int bi = 0; bi < 16; ++bi) {
            int b = bg * 16 + bi;
            *(float2*)&sc[(size_t)(b * 32 + sl) * 18 + rrg * 2] =
                make_float2(acc[0][bi], acc[1][bi]);
        }
        __syncthreads();

        // reduce over 32 slices (rotated to dodge bank alias), add xg
        {
            int rr = tau & 15, b = tau >> 4;
            float s = 0.f;
#pragma unroll
            for (int j = 0; j < 32; ++j)
                s += sc[(size_t)(b * 32 + ((j + b) & 31)) * 18 + rr];
            s += xg_t[b * FH + (rr >> 2) * H_ + hc0 + (rr & 3)];
            g[rr * 32 + b] = s;
        }
        __syncthreads();

        // activation: thread b handles its 4 cols; c in registers
        if (tau < 32) {
            int b = tau;
            float4 hv4;
            float* cc = (float*)&creg;
            float* hh = (float*)&hv4;
#pragma unroll
            for (int col = 0; col < 4; ++col) {
                float vi = g[(0 * 4 + col) * 32 + b];
                float vf = g[(1 * 4 + col) * 32 + b];
                float vg = g[(2 * 4 + col) * 32 + b];
                float vo = g[(3 * 4 + col) * 32 + b];
                float si = 1.f / (1.f + __expf(-vi));
                float sf = 1.f / (1.f + __expf(-vf));
                float so = 1.f / (1.f + __expf(-vo));
                float ag = fabsf(vg), eg = __expf(-2.f * ag);
                float tg = (1.f - eg) / (1.f + eg); tg = vg < 0.f ? -tg : tg;
                float cn = sf * cc[col] + si * tg;
                cc[col] = cn;
                float ac = fabsf(cn), ec = __expf(-2.f * ac);
                float th = (1.f - ec) / (1.f + ec); th = cn < 0.f ? -th : th;
                hh[col] = so * th;
            }
            ((float4*)hn)[b * 256 + blk] = hv4;
            ((float4*)y)[(size_t)b * (T_ * H_ / 4) + t * (H_ / 4) + blk] = hv4;
        }
        __syncthreads();   // every wave drains its own stores (vmcnt) here
        if (tau == 0) {
            // publish: writeback/flush once, then bypassing flag store
            __builtin_amdgcn_fence(__ATOMIC_RELEASE, "agent");
            __hip_atomic_store(flags + blk, (unsigned)(t + 1), __ATOMIC_RELAXED,
                               __HIP_MEMORY_SCOPE_AGENT);
        }
    }

    if (tau < 32) ((float4*)cbuf)[tau * 256 + blk] = creg;
}

// ---------------------------------------------------------------------------
extern "C" void kernel_launch(void* const* d_in, const int* in_sizes, int n_in,
                              void* d_out, int out_size, void* d_ws, size_t ws_size,
                              hipStream_t stream) {
    (void)in_sizes; (void)n_in; (void)out_size;
    const float* x   = (const float*)d_in[0];
    const float* Wx0 = (const float*)d_in[1];
    const float* Wh0 = (const float*)d_in[2];
    const float* b0  = (const float*)d_in[3];
    const float* Wx1 = (const float*)d_in[4];
    const float* Wh1 = (const float*)d_in[5];
    const float* b1  = (const float*)d_in[6];
    float* out = (float*)d_out;

    char* ws = (char*)d_ws;
    float*    wht   = (float*)(ws);
    float*    hbuf  = (float*)(ws + 16777216ull);
    float*    cbuf  = (float*)(ws + 17039360ull);
    unsigned* flags = (unsigned*)(ws + 17170432ull);
    float*    xgc   = (float*)(ws + 17174528ull);

    const size_t base = 17174528ull;
    int Tc;
    if      (ws_size >= base + 512ull * 524288ull) Tc = 512;
    else if (ws_size >= base + 128ull * 524288ull) Tc = 128;
    else if (ws_size >= base +  64ull * 524288ull) Tc = 64;
    else if (ws_size >= base +  16ull * 524288ull) Tc = 16;
    else                                           Tc = 4;

    for (int layer = 0; layer < 2; ++layer) {
        const float* Aptr = layer ? out : x;
        const float* Wxp  = layer ? Wx1 : Wx0;
        const float* Whp  = layer ? Wh1 : Wh0;
        const float* bp   = layer ? b1  : b0;
        const int    K    = layer ? H_  : D_;

        transpose_wh<<<dim3(128, 32), dim3(32, 8), 0, stream>>>(Whp, wht);
        (void)hipMemsetAsync(hbuf, 0, 262144, stream);
        (void)hipMemsetAsync(cbuf, 0, 131072, stream);
        (void)hipMemsetAsync(flags, 0, 4096, stream);

        for (int t0 = 0; t0 < T_; t0 += Tc) {
            // Layer 1 reads out[] rows t in [t0,t0+Tc) only — rows its own
            // scan hasn't overwritten yet -> stream-order safe.
            gemm_bias_chunk<<<dim3(32, Tc / 2), 256, 0, stream>>>(
                Aptr, Wxp, bp, xgc, K, t0);
            lstm_scan<<<256, 512, 0, stream>>>(
                wht, xgc, hbuf, cbuf, flags, out, t0, Tc);
        }
    }
}